// Round 3
// baseline (1346.304 us; speedup 1.0000x reference)
//
#include <hip/hip_runtime.h>
#include <hip/hip_bf16.h>

// Problem constants
#define NT    1024   // tokens
#define HDIM  2048
#define NEXP  64
#define IDIM  512
#define ISDIM 1024
#define KTOP  8
#define ECAP  256

typedef float  f32x4 __attribute__((ext_vector_type(4)));
typedef __bf16 bf16x8 __attribute__((ext_vector_type(8)));
typedef unsigned short u16x8 __attribute__((ext_vector_type(8)));

// k-group slot within a 32-short row: phase-conflict-free XOR swizzle.
#define SWZ(r, q) ((((q) ^ ((r) & 3) ^ (((r) >> 2) & 3)) & 3) << 3)

static __device__ __forceinline__ unsigned short f2b(float f) {
  __hip_bfloat16 h = __float2bfloat16(f);
  return __builtin_bit_cast(unsigned short, h);
}
static __device__ __forceinline__ float b2f(unsigned short u) {
  return __bfloat162float(__builtin_bit_cast(__hip_bfloat16, u));
}
// async global->LDS 16B copy: per-lane global src, wave-uniform LDS base
static __device__ __forceinline__ void gload16(const unsigned short* g, unsigned short* l) {
  __builtin_amdgcn_global_load_lds(
      (const __attribute__((address_space(1))) unsigned int*)g,
      (__attribute__((address_space(3))) unsigned int*)l, 16, 0, 0);
}

// ---------------------------------------------------------------------------
// Router: logits fp32, top-8, renormalized softmax, expert lists, sigmoid gate
// ---------------------------------------------------------------------------
__global__ __launch_bounds__(256) void k_router(
    const float* __restrict__ x, const float* __restrict__ gw,
    const float* __restrict__ wsg,
    int* __restrict__ counts, int* __restrict__ tok_list,
    int* __restrict__ slot_map, float* __restrict__ wgt_map,
    float* __restrict__ gate_sig)
{
  __shared__ float xs[HDIM];
  __shared__ float lg[NEXP];
  __shared__ float selv[KTOP];
  __shared__ int   sele[KTOP];
  const int t = blockIdx.x, tid = threadIdx.x;
  const float* xr = x + (size_t)t * HDIM;
  for (int i = tid; i < HDIM / 4; i += 256)
    ((f32x4*)xs)[i] = ((const f32x4*)xr)[i];
  __syncthreads();
  const int wave = tid >> 6, lane = tid & 63;
  for (int ei = 0; ei < 16; ++ei) {
    const int e = wave * 16 + ei;
    const float* g = gw + (size_t)e * HDIM;
    float s = 0.f;
    for (int j = lane; j < HDIM; j += 64) s += xs[j] * g[j];
    for (int off = 32; off; off >>= 1) s += __shfl_xor(s, off, 64);
    if (lane == 0) lg[e] = s;
  }
  if (wave == 1) {
    float s = 0.f;
    for (int j = lane; j < HDIM; j += 64) s += xs[j] * wsg[j];
    for (int off = 32; off; off >>= 1) s += __shfl_xor(s, off, 64);
    if (lane == 0) gate_sig[t] = 1.f / (1.f + __expf(-s));
  }
  __syncthreads();
  if (wave == 0) {
    float v = lg[lane];
    for (int k = 0; k < KTOP; ++k) {
      float m = v;
      for (int off = 32; off; off >>= 1) m = fmaxf(m, __shfl_xor(m, off, 64));
      unsigned long long msk = __ballot(v == m);
      int src = __ffsll(msk) - 1;
      if (lane == src) v = -3.4e38f;
      if (lane == 0) { selv[k] = m; sele[k] = src; }
    }
  }
  __syncthreads();
  if (tid < KTOP) {
    const int k = tid;
    const float mx = selv[0];
    float sum = 0.f;
    for (int i = 0; i < KTOP; ++i) sum += __expf(selv[i] - mx);
    const float w = __expf(selv[k] - mx) / sum;
    const int e = sele[k];
    const int pos = atomicAdd(&counts[e], 1);
    int slot = -1;
    if (pos < ECAP) { slot = e * ECAP + pos; tok_list[slot] = t; }
    slot_map[t * KTOP + k] = slot;
    wgt_map[t * KTOP + k] = w;
  }
}

// ---------------------------------------------------------------------------
// Weight convert+relayout: row-major [K][N] fp32 -> bf16 tile images.
// Tile = TW cols x 32 k, image[n][slot j]: slot j holds k-group
// kg = j ^ (n&3) ^ ((n>>2)&3)  (matches GEMM LDS layout, so GEMM staging is a
// linear global_load_lds copy). dst layout: [N/TW][K/32][TW*32].
// Block: 32 k-rows x 512 cols. Reads fully contiguous; writes coalesced 16B.
// ---------------------------------------------------------------------------
__global__ __launch_bounds__(256) void k_tile(
    const float* __restrict__ src, unsigned short* __restrict__ dst,
    const int K, const int N, const int tw128)
{
  __shared__ float sb[32 * 512];  // 64KB, bank-swizzled: [r][c ^ ((r&7)<<2)]
  const int nsh = (N >= 2048) ? 2 : (N >= 1024 ? 1 : 0);
  const int kt = blockIdx.x >> nsh;
  const int nc = blockIdx.x & ((1 << nsh) - 1);
  const int ktiles = K >> 5;
  const int tshift = tw128 ? 9 : 8;          // 16B-chunks per tile
  const int tw = tw128 ? 128 : 64;
  const size_t tile_shorts = tw128 ? 4096 : 2048;
  const size_t moff_src = (size_t)blockIdx.y * K * N;
  const size_t moff_dst = (size_t)blockIdx.y * (size_t)(N >> (tw128 ? 7 : 6)) * ktiles * tile_shorts;
  const int tid = threadIdx.x;
  const float* s0 = src + moff_src + (size_t)kt * 32 * N + (size_t)nc * 512;
  for (int i = tid; i < 4096; i += 256) {
    const int r = i >> 7, c4 = (i & 127) << 2;
    const f32x4 v = *(const f32x4*)(s0 + (size_t)r * N + c4);
    *(f32x4*)&sb[r * 512 + (c4 ^ ((r & 7) << 2))] = v;
  }
  __syncthreads();
  unsigned short* d0 = dst + moff_dst;
#pragma unroll
  for (int s = 0; s < 8; ++s) {
    const int c = s * 256 + tid;             // 0..2047 16B-chunks
    const int ntl = c >> tshift;             // tile within 512-col chunk
    const int cc = c & ((1 << tshift) - 1);
    const int off = cc * 8;                  // short offset in tile image
    const int n = off >> 5;                  // row (col of W) in tile
    const int j = (off >> 3) & 3;            // slot
    const int kg = (j ^ (n & 3) ^ ((n >> 2) & 3)) & 3;
    const int gcol = ntl * tw + n;           // col within 512-chunk
    u16x8 p;
#pragma unroll
    for (int i2 = 0; i2 < 8; ++i2) {
      const int r = kg * 8 + i2;
      p[i2] = f2b(sb[r * 512 + (gcol ^ ((r & 7) << 2))]);
    }
    const int ntg = nc * (512 >> (tw128 ? 7 : 6)) + ntl;
    *(u16x8*)(d0 + ((size_t)ntg * ktiles + kt) * tile_shorts + off) = p;
  }
}

// ---------------------------------------------------------------------------
// GEMM1: h = silu(X@W1)*(X@W3). BM=256, BN=64, BK=32, 512 thr (4m x 2n waves).
// B staged via global_load_lds from pre-tiled bf16 images (triple-buffered,
// counted vmcnt keeps prefetch in flight across lgkm-only barrier).
// A (gathered x rows, fp32) staged via regs + swizzled ds_write (dbuf).
// Output written in GEMM2's A-tile image format.
// ---------------------------------------------------------------------------
__global__ __launch_bounds__(512, 4) void k_gemm1(
    const float* __restrict__ x,
    const unsigned short* __restrict__ w1t, const unsigned short* __restrict__ w3t,
    const unsigned short* __restrict__ ws1t, const unsigned short* __restrict__ ws3t,
    const int* __restrict__ counts, const int* __restrict__ tok_list,
    unsigned short* __restrict__ hbuf, unsigned short* __restrict__ hsbuf)
{
  extern __shared__ unsigned short lds[];
  // shorts: A dbuf [2][8192] @0 ; B1 [3][2048] @16384 ; B3 [3][2048] @22528
  const int cpx = gridDim.x >> 3;          // 576/8 = 72
  const int b0 = blockIdx.x;
  const int bid = (b0 & 7) * cpx + (b0 >> 3);
  const int tid = threadIdx.x;
  bool is_exp; int g = 0, nt, me, m0s = 0;
  const unsigned short *b1t, *b3t;
  if (bid < NEXP * 8) {                    // 64 experts x 8 ntiles (IDIM/64)
    is_exp = true; g = bid >> 3; nt = bid & 7;
    me = counts[g]; me = me < ECAP ? me : ECAP;
    if (me == 0) return;
    b1t = w1t + (size_t)(g * 8 + nt) * (64 * 2048);
    b3t = w3t + (size_t)(g * 8 + nt) * (64 * 2048);
  } else {
    is_exp = false;
    const int s = bid - NEXP * 8;          // 0..63 = 16nt x 4mt
    nt = s >> 2; m0s = (s & 3) * 256; me = 256;
    b1t = ws1t + (size_t)nt * (64 * 2048);
    b3t = ws3t + (size_t)nt * (64 * 2048);
  }
  const int n0 = nt * 64;
  // ---- A staging: 2 threads/row, 16 fp32 each ----
  const int ar = tid & 255, sel2 = tid >> 8;
  const bool avalid = is_exp ? (ar < me) : true;
  const float* arow;
  if (is_exp) {
    const int tok = avalid ? tok_list[g * ECAP + ar] : 0;
    arow = x + (size_t)tok * HDIM + sel2 * 16;
  } else {
    arow = x + (size_t)(m0s + ar) * HDIM + sel2 * 16;
  }
  const int ag0 = sel2 * 2;
  const int aoff0 = ar * 32 + SWZ(ar, ag0);
  const int aoff1 = ar * 32 + SWZ(ar, ag0 + 1);
  // ---- B staging: one gload16/thread (waves 0-3 -> B1, 4-7 -> B3) ----
  const int bsub = tid & 255;
  const unsigned short* btile = (tid < 256) ? b1t : b3t;
  const int bbase = (tid < 256) ? 16384 : 22528;
  const int bwq = bsub >> 6;               // wave-uniform quarter
  // ---- fragments: 8 waves = 4m x 2n, wave tile 64x32 ----
  const int lane = tid & 63, quad = lane >> 4, l15 = lane & 15;
  const int wv = tid >> 6, wm = wv >> 1, wn = wv & 1;
  const bool wactive = is_exp ? (wm * 64 < me) : true;
  int aro[4], bo[2];
#pragma unroll
  for (int i = 0; i < 4; ++i) {
    const int rr = wm * 64 + i * 16 + l15;
    aro[i] = rr * 32 + SWZ(rr, quad);
  }
#pragma unroll
  for (int j = 0; j < 2; ++j) {
    const int nn = wn * 32 + j * 16 + l15;
    bo[j] = nn * 32 + SWZ(nn, quad);
  }
  f32x4 acc1[4][2], acc3[4][2];
#pragma unroll
  for (int i = 0; i < 4; ++i)
#pragma unroll
    for (int j = 0; j < 2; ++j) {
      acc1[i][j] = f32x4{0.f, 0.f, 0.f, 0.f};
      acc3[i][j] = f32x4{0.f, 0.f, 0.f, 0.f};
    }
  f32x4 a0, a1, a2, a3;
  const int KT = HDIM / 32;                // 64
  // prologue: B(0) -> slot0, A(0) -> regs
  gload16(btile + bsub * 8, lds + bbase + bwq * 512);
  { const f32x4* ap = (const f32x4*)arow;
    a0 = ap[0]; a1 = ap[1]; a2 = ap[2]; a3 = ap[3]; }
  int sc = 0, sn = 1;
  for (int kt = 0; kt < KT; ++kt) {
    unsigned short* A = lds + (kt & 1) * 8192;
    {   // write stage (compiler inserts vmcnt wait for a0..a3 -> drains B(kt))
      u16x8 p0, p1;
#pragma unroll
      for (int i = 0; i < 4; ++i) {
        p0[i] = f2b(a0[i]); p0[4 + i] = f2b(a1[i]);
        p1[i] = f2b(a2[i]); p1[4 + i] = f2b(a3[i]);
      }
      *(u16x8*)&A[aoff0] = p0;
      *(u16x8*)&A[aoff1] = p1;
    }
    if (kt + 1 < KT) {   // prefetch: 1 gload + 4 f32x4 (5 VMEM, counted below)
      gload16(btile + (size_t)(kt + 1) * 2048 + bsub * 8,
              lds + bbase + sn * 2048 + bwq * 512);
      const f32x4* ap = (const f32x4*)(arow + (kt + 1) * 32);
      a0 = ap[0]; a1 = ap[1]; a2 = ap[2]; a3 = ap[3];
    }
    // only the 5 newest VMEM (next-tile) may stay in flight across the barrier
    asm volatile("s_waitcnt vmcnt(5) lgkmcnt(0)" ::: "memory");
    __builtin_amdgcn_s_barrier();
    if (wactive) {
      const unsigned short* B1 = lds + 16384 + sc * 2048;
      const unsigned short* B3 = lds + 22528 + sc * 2048;
      bf16x8 af[4], bb1[2], bb3[2];
#pragma unroll
      for (int j = 0; j < 2; ++j) {
        bb1[j] = __builtin_bit_cast(bf16x8, *(const u16x8*)&B1[bo[j]]);
        bb3[j] = __builtin_bit_cast(bf16x8, *(const u16x8*)&B3[bo[j]]);
      }
#pragma unroll
      for (int i = 0; i < 4; ++i)
        af[i] = __builtin_bit_cast(bf16x8, *(const u16x8*)&A[aro[i]]);
#pragma unroll
      for (int i = 0; i < 4; ++i)
#pragma unroll
        for (int j = 0; j < 2; ++j) {
          acc1[i][j] = __builtin_amdgcn_mfma_f32_16x16x32_bf16(af[i], bb1[j], acc1[i][j], 0, 0, 0);
          acc3[i][j] = __builtin_amdgcn_mfma_f32_16x16x32_bf16(af[i], bb3[j], acc3[i][j], 0, 0, 0);
        }
    }
    sc = sn; sn = (sn + 1 == 3) ? 0 : sn + 1;
  }
  // epilogue: h = silu(c1)*c3 -> bf16, written in GEMM2 A-tile image format
  if (wactive) {
#pragma unroll
    for (int i = 0; i < 4; ++i) {
#pragma unroll
      for (int q = 0; q < 4; ++q) {
        const int rr = wm * 64 + i * 16 + quad * 4 + q;
        if (is_exp && rr >= me) continue;
#pragma unroll
        for (int j = 0; j < 2; ++j) {
          const int col = n0 + wn * 32 + j * 16 + l15;
          const float gg = acc1[i][j][q];
          const float uu = acc3[i][j][q];
          const float sv = (gg / (1.f + __expf(-gg))) * uu;
          const int kti = col >> 5, kk = col & 31;
          if (is_exp) {
            const int sl = ((kk >> 3) ^ (rr & 3) ^ ((rr >> 2) & 3)) & 3;
            hbuf[(((size_t)g * 16 + kti) * 256 + rr) * 32 + sl * 8 + (kk & 7)] = f2b(sv);
          } else {
            const int grow = m0s + rr;
            const int sl = ((kk >> 3) ^ (grow & 3) ^ ((grow >> 2) & 3)) & 3;
            hsbuf[((size_t)kti * 1024 + grow) * 32 + sl * 8 + (kk & 7)] = f2b(sv);
          }
        }
      }
    }
  }
}

// ---------------------------------------------------------------------------
// GEMM2: yb = h@W2 (experts) / out = gate*(hs@ws2) (shared).
// BM=256, BN=128, BK=32. Both A and B staged via global_load_lds from tile
// images (3 VMEM instr/thread/iter, triple-buffered, counted vmcnt).
// ---------------------------------------------------------------------------
__global__ __launch_bounds__(512, 4) void k_gemm2(
    const unsigned short* __restrict__ hbuf, const unsigned short* __restrict__ hsbuf,
    const unsigned short* __restrict__ w2t, const unsigned short* __restrict__ ws2t,
    const int* __restrict__ counts, const float* __restrict__ gate_sig,
    unsigned short* __restrict__ yb, float* __restrict__ out)
{
  extern __shared__ unsigned short lds[];
  // shorts: A [3][8192] @0 ; B [3][4096] @24576
  const int cpx = gridDim.x >> 3;          // 1088/8 = 136
  const int b0 = blockIdx.x;
  const int bid = (b0 & 7) * cpx + (b0 >> 3);
  const int tid = threadIdx.x;
  bool is_exp; int g = 0, nt, me, m0s = 0, KT, astr;
  const unsigned short *atile, *btile;
  if (bid < NEXP * 16) {                   // 64 experts x 16 ntiles (HDIM/128)
    is_exp = true; g = bid >> 4; nt = bid & 15;
    me = counts[g]; me = me < ECAP ? me : ECAP;
    if (me == 0) return;
    KT = IDIM / 32; astr = 8192;
    atile = hbuf + (size_t)g * 16 * 8192;
    btile = w2t + (size_t)(g * 16 + nt) * (16 * 4096);
  } else {
    is_exp = false;
    const int s = bid - NEXP * 16;         // 0..63 = 16nt x 4mt
    nt = s >> 2; m0s = (s & 3) * 256; me = 256;
    KT = ISDIM / 32; astr = 32768;
    atile = hsbuf + (size_t)m0s * 32;
    btile = ws2t + (size_t)nt * (32 * 4096);
  }
  const int n0 = nt * 128;
  const int lane = tid & 63, quad = lane >> 4, l15 = lane & 15;
  const int wv = tid >> 6, wm = wv >> 1, wn = wv & 1;
  const bool wactive = is_exp ? (wm * 64 < me) : true;
  int aro[4], bo[4];
#pragma unroll
  for (int i = 0; i < 4; ++i) {
    const int rr = wm * 64 + i * 16 + l15;
    aro[i] = rr * 32 + SWZ(rr, quad);
  }
#pragma unroll
  for (int j = 0; j < 4; ++j) {
    const int nn = wn * 64 + j * 16 + l15;
    bo[j] = nn * 32 + SWZ(nn, quad);
  }
  f32x4 acc[4][4];
#pragma unroll
  for (int i = 0; i < 4; ++i)
#pragma unroll
    for (int j = 0; j < 4; ++j) acc[i][j] = f32x4{0.f, 0.f, 0.f, 0.f};
  // prologue: stage tile 0 into slot 0
  gload16(atile + tid * 8,        lds + wv * 512);
  gload16(atile + 4096 + tid * 8, lds + 4096 + wv * 512);
  gload16(btile + tid * 8,        lds + 24576 + wv * 512);
  int sc = 0, sn = 1;
  for (int kt = 0; kt < KT; ++kt) {
    if (kt + 1 < KT) {
      const unsigned short* an = atile + (size_t)(kt + 1) * astr;
      gload16(an + tid * 8,        lds + sn * 8192 + wv * 512);
      gload16(an + 4096 + tid * 8, lds + sn * 8192 + 4096 + wv * 512);
      gload16(btile + (size_t)(kt + 1) * 4096 + tid * 8,
              lds + 24576 + sn * 4096 + wv * 512);
      asm volatile("s_waitcnt vmcnt(3)" ::: "memory");
    } else {
      asm volatile("s_waitcnt vmcnt(0)" ::: "memory");
    }
    __builtin_amdgcn_s_barrier();
    if (wactive) {
      const unsigned short* A = lds + sc * 8192;
      const unsigned short* B = lds + 24576 + sc * 4096;
      bf16x8 af[4], bf[4];
#pragma unroll
      for (int j = 0; j < 4; ++j)
        bf[j] = __builtin_bit_cast(bf16x8, *(const u16x8*)&B[bo[j]]);
#pragma unroll
      for (int i = 0; i < 4; ++i)
        af[i] = __builtin_bit_cast(bf16x8, *(const u16x8*)&A[aro[i]]);
#pragma unroll
      for (int i = 0; i < 4; ++i)
#pragma unroll
        for (int j = 0; j < 4; ++j)
          acc[i][j] = __builtin_amdgcn_mfma_f32_16x16x32_bf16(af[i], bf[j], acc[i][j], 0, 0, 0);
    }
    sc = sn; sn = (sn + 1 == 3) ? 0 : sn + 1;
  }
  if (wactive) {
#pragma unroll
    for (int i = 0; i < 4; ++i) {
#pragma unroll
      for (int q = 0; q < 4; ++q) {
        const int rr = wm * 64 + i * 16 + quad * 4 + q;
        if (is_exp) {
          if (rr >= me) continue;
          unsigned short* orow = yb + ((size_t)g * ECAP + rr) * HDIM;
#pragma unroll
          for (int j = 0; j < 4; ++j) {
            const int col = n0 + wn * 64 + j * 16 + l15;
            orow[col] = f2b(acc[i][j][q]);
          }
        } else {
          const int grow = m0s + rr;
          const float gt = gate_sig[grow];
          float* orow = out + (size_t)grow * HDIM;
#pragma unroll
          for (int j = 0; j < 4; ++j) {
            const int col = n0 + wn * 64 + j * 16 + l15;
            orow[col] = gt * acc[i][j][q];
          }
        }
      }
    }
  }
}

// ---------------------------------------------------------------------------
// Combine: out[t] += sum_k w_k * yb[slot_k]
// ---------------------------------------------------------------------------
__global__ __launch_bounds__(256) void k_combine(
    const unsigned short* __restrict__ yb,
    const int* __restrict__ slot_map, const float* __restrict__ wgt_map,
    float* __restrict__ out)
{
  __shared__ int ss[KTOP];
  __shared__ float ww[KTOP];
  const int t = blockIdx.x, tid = threadIdx.x;
  if (tid < KTOP) { ss[tid] = slot_map[t * KTOP + tid]; ww[tid] = wgt_map[t * KTOP + tid]; }
  __syncthreads();
  const int c = tid * 8;
  float* op = out + (size_t)t * HDIM + c;
  f32x4 o0 = ((const f32x4*)op)[0];
  f32x4 o1 = ((const f32x4*)op)[1];
  for (int k = 0; k < KTOP; ++k) {
    const int s = ss[k];
    if (s < 0) continue;
    const float w = ww[k];
    const u16x8 y = *(const u16x8*)(yb + (size_t)s * HDIM + c);
#pragma unroll
    for (int i = 0; i < 4; ++i) {
      o0[i] += w * b2f(y[i]);
      o1[i] += w * b2f(y[4 + i]);
    }
  }
  ((f32x4*)op)[0] = o0;
  ((f32x4*)op)[1] = o1;
}

// ---------------------------------------------------------------------------
extern "C" void kernel_launch(void* const* d_in, const int* in_sizes, int n_in,
                              void* d_out, int out_size, void* d_ws, size_t ws_size,
                              hipStream_t stream) {
  (void)in_sizes; (void)n_in; (void)out_size; (void)ws_size;
  const float* x   = (const float*)d_in[0];
  const float* gw  = (const float*)d_in[1];
  const float* w1  = (const float*)d_in[2];
  const float* w3  = (const float*)d_in[3];
  const float* w2  = (const float*)d_in[4];
  const float* ws1 = (const float*)d_in[5];
  const float* ws3 = (const float*)d_in[6];
  const float* ws2 = (const float*)d_in[7];
  const float* wsg = (const float*)d_in[8];
  float* out = (float*)d_out;
  char* ws = (char*)d_ws;
  const size_t MiB = (size_t)1 << 20;
  // workspace layout (peak ~288 MiB):
  int*   counts   = (int*)ws;                          // 256 B
  int*   tok_list = (int*)(ws + 256);                  // 64 KB
  int*   slot_map = (int*)(ws + 256 + (64 << 10));     // 32 KB
  float* wgt_map  = (float*)(ws + 256 + (96 << 10));   // 32 KB
  float* gate_sig = (float*)(ws + 256 + (128 << 10));  // 4 KB
  unsigned short* hbuf  = (unsigned short*)(ws + 1 * MiB);    // 16 MiB (tiled)
  unsigned short* hsbuf = (unsigned short*)(ws + 17 * MiB);   // 2 MiB (tiled)
  unsigned short* ws1t  = (unsigned short*)(ws + 19 * MiB);   // 4 MiB
  unsigned short* ws3t  = (unsigned short*)(ws + 23 * MiB);   // 4 MiB
  unsigned short* ws2t  = (unsigned short*)(ws + 27 * MiB);   // 4 MiB
  unsigned short* w1t   = (unsigned short*)(ws + 32 * MiB);   // 128 MiB
  unsigned short* w3t   = (unsigned short*)(ws + 160 * MiB);  // 128 MiB
  unsigned short* w2t   = w1t;   // reuse W1T region after gemm1
  unsigned short* yb    = (unsigned short*)(ws + 160 * MiB);  // reuse W3T (64 MiB)

  hipMemsetAsync(counts, 0, 256, stream);
  k_router<<<dim3(NT), dim3(256), 0, stream>>>(x, gw, wsg, counts, tok_list,
                                               slot_map, wgt_map, gate_sig);
  k_tile<<<dim3(64, 64), dim3(256), 0, stream>>>(w1, w1t, HDIM, IDIM, 0);
  k_tile<<<dim3(64, 64), dim3(256), 0, stream>>>(w3, w3t, HDIM, IDIM, 0);
  k_tile<<<dim3(128, 1), dim3(256), 0, stream>>>(ws1, ws1t, HDIM, ISDIM, 0);
  k_tile<<<dim3(128, 1), dim3(256), 0, stream>>>(ws3, ws3t, HDIM, ISDIM, 0);
  k_tile<<<dim3(128, 1), dim3(256), 0, stream>>>(ws2, ws2t, ISDIM, HDIM, 1);
  k_gemm1<<<dim3(NEXP * 8 + 64), dim3(512), 57344, stream>>>(
      x, w1t, w3t, ws1t, ws3t, counts, tok_list, hbuf, hsbuf);
  k_tile<<<dim3(64, 64), dim3(256), 0, stream>>>(w2, w2t, IDIM, HDIM, 1);
  k_gemm2<<<dim3(NEXP * 16 + 64), dim3(512), 73728, stream>>>(
      hbuf, hsbuf, w2t, ws2t, counts, gate_sig, yb, out);
  k_combine<<<dim3(NT), dim3(256), 0, stream>>>(yb, slot_map, wgt_map, out);
}